// Round 19
// baseline (305.181 us; speedup 1.0000x reference)
//
#include <hip/hip_runtime.h>
#include <hip/hip_bf16.h>
#include <math.h>

#define A_TOK 4096
#define DDIM  1024
#define NEXP  8
#define FDIM  2816
#define KSPL  1408         // virtual K = 2*FDIM = 5632; per split = 22*64

typedef __bf16 bf16_t;
typedef __bf16 bf16x8 __attribute__((ext_vector_type(8)));
typedef __bf16 bf16x4 __attribute__((ext_vector_type(4)));
typedef __bf16 bf16x2 __attribute__((ext_vector_type(2)));
typedef float  f32x4  __attribute__((ext_vector_type(4)));

// ======================= workspace layout =======================
static constexpr size_t OFF_XS   = 65536;
static constexpr size_t OFF_XR   = OFF_XS   + (size_t)A_TOK * DDIM * 2;
static constexpr size_t OFF_MIDS = OFF_XR   + (size_t)(A_TOK + 128) * DDIM * 2;
static constexpr size_t OFF_MIDR = OFF_MIDS + (size_t)A_TOK * FDIM * 2;
static constexpr size_t OFF_W1T  = OFF_MIDR + (size_t)(A_TOK + 128) * FDIM * 2;
static constexpr size_t OFF_W3T  = OFF_W1T  + (size_t)NEXP * DDIM * FDIM * 2;
static constexpr size_t OFF_W2T  = OFF_W3T  + (size_t)NEXP * DDIM * FDIM * 2;
static constexpr size_t OFF_WS1T = OFF_W2T  + (size_t)NEXP * DDIM * FDIM * 2;
static constexpr size_t OFF_WS3T = OFF_WS1T + (size_t)DDIM * FDIM * 2;
static constexpr size_t OFF_WS2T = OFF_WS3T + (size_t)DDIM * FDIM * 2;
static constexpr size_t WS_NEED  = OFF_WS2T + (size_t)DDIM * FDIM * 2;   // ~209.5 MiB
// Split-K partials (bf16, 8.4MB each) alias the dead w1T region (last read by
// the gemm1 launch, which completes before gemm2c runs).
static constexpr size_t OFF_OUTP1 = OFF_W1T;
static constexpr size_t OFF_OUTP2 = OFF_OUTP1 + (size_t)A_TOK * DDIM * 2;
static constexpr size_t OFF_OUTP3 = OFF_OUTP2 + (size_t)A_TOK * DDIM * 2;

// Tuning ledger (measured):
//  R3: BK=64, 8-slot XOR swizzle, (256,2) -> gemm1 120.7us / 783 TF. Working pt.
//  R4: BK=32 dbuf -> REGRESSED; root cause was the 4-slot swizzle's 4-way
//      conflicts (BK=32 has only 2 bank-base bits), NOT the dbuf idiom.
//  R5: XCD remap -> slower (latency-bound). REVERTED.
//  R6: launch_bounds(256,3) -> spills. REVERTED.
//  R7-R14: gemm2 ladder 180 -> ~72us (K-concat + splitK4). R15: 311.8.
//  R16: heterogeneous riders (tconvB in gemm1, prep in tconvA) -> 298.4.
//  R17: splitting gemm1 to hide tconvA -> REGRESSED (compute must >> riders).
//  R18: tconvA 2-tile + nontemporal loads -> 293.0 BEST. tconvA near BW floor.
//  R19: gemm2c 2-phase dbuf at BK=64 (recipe: STAGE(next) before COMPUTE(cur),
//       ONE barrier/K-step, 44->23 barriers; 64KB LDS keeps 2 blocks/CU).
//       gemm1 can't take dbuf (96KB -> 1 block/CU trap) (this round).

// ======================= router: scores =======================
__global__ __launch_bounds__(256)
void score_kernel(const float* __restrict__ x,
                  const float* __restrict__ router,
                  int* __restrict__ idx_a,
                  float* __restrict__ gate_a)
{
    __shared__ float rT[NEXP][DDIM];
    const int tid = threadIdx.x;
    for (int i = tid; i < DDIM * NEXP; i += 256)
        rT[i & 7][i >> 3] = router[i];
    __syncthreads();

    const int wid = tid >> 6, lane = tid & 63;
    const int t = blockIdx.x * 4 + wid;
    const float* xr = x + (size_t)t * DDIM;

    double s[NEXP];
#pragma unroll
    for (int e = 0; e < NEXP; ++e) s[e] = 0.0;
#pragma unroll
    for (int i = 0; i < DDIM / 64; ++i) {
        int d = i * 64 + lane;
        float xv = xr[d];
#pragma unroll
        for (int e = 0; e < NEXP; ++e)
            s[e] += (double)xv * (double)rT[e][d];
    }
#pragma unroll
    for (int e = 0; e < NEXP; ++e) {
#pragma unroll
        for (int off = 32; off > 0; off >>= 1)
            s[e] += __shfl_xor(s[e], off);
    }
    if (lane == 0) {
        int best = 0; double bv = s[0];
#pragma unroll
        for (int e = 1; e < NEXP; ++e)
            if (s[e] > bv) { bv = s[e]; best = e; }
        idx_a[t] = best;
        gate_a[t] = 1.0f / (1.0f + expf(-(float)bv));
    }
}

// ======================= fused count + scan + scatter =======================
__global__ __launch_bounds__(1024)
void perm_kernel(const int* __restrict__ idx_a,
                 int* __restrict__ offsets,
                 int* __restrict__ perm)
{
    __shared__ int cnt[NEXP];
    __shared__ int base[NEXP];
    const int tid = threadIdx.x;
    if (tid < NEXP) cnt[tid] = 0;
    __syncthreads();

    int e[4];
#pragma unroll
    for (int j = 0; j < 4; ++j) {
        e[j] = idx_a[j * 1024 + tid];
        atomicAdd(&cnt[e[j]], 1);
    }
    __syncthreads();
    if (tid == 0) {
        int acc = 0;
#pragma unroll
        for (int k = 0; k < NEXP; ++k) {
            base[k] = acc; offsets[k] = acc; acc += cnt[k];
        }
        offsets[NEXP] = acc;
    }
    __syncthreads();
#pragma unroll
    for (int j = 0; j < 4; ++j) {
        int t = j * 1024 + tid;
        int pos = atomicAdd(&base[e[j]], 1);
        perm[pos] = t;
    }
}

// ======================= helpers =======================
__device__ __forceinline__ unsigned pk2(float a, float b)
{
    union { bf16x2 v; unsigned u; } x;
    x.v[0] = (bf16_t)a; x.v[1] = (bf16_t)b;
    return x.u;
}

__device__ __forceinline__ f32x4 ntload4(const float* p)
{
    return __builtin_nontemporal_load((const f32x4*)p);
}

// single-tile transpose+convert: src [R][C] fp32 -> dst [C][R] bf16, 64x64.
__device__ __forceinline__ void tconv_tile(const float* __restrict__ src,
                                           bf16_t* __restrict__ dst,
                                           int R, int C, int r0, int c0,
                                           unsigned (*t2)[33])
{
    const int tid = threadIdx.x;
    const int cl = (tid & 15) * 4;
    const int rh = tid >> 4;
#pragma unroll
    for (int i = 0; i < 2; ++i) {
        const int r = rh * 2 + i * 32;
        const float* s0 = src + (size_t)(r0 + r) * C + c0 + cl;
        f32x4 v0 = ntload4(s0);
        f32x4 v1 = ntload4(s0 + C);
        t2[cl + 0][rh + i * 16] = pk2(v0[0], v1[0]);
        t2[cl + 1][rh + i * 16] = pk2(v0[1], v1[1]);
        t2[cl + 2][rh + i * 16] = pk2(v0[2], v1[2]);
        t2[cl + 3][rh + i * 16] = pk2(v0[3], v1[3]);
    }
    __syncthreads();
    const int c2 = tid >> 3;
    const int rq = (tid & 7) * 4;
#pragma unroll
    for (int i = 0; i < 2; ++i) {
        const int c = c2 + i * 32;
        uint4 vv;
        vv.x = t2[c][rq + 0];
        vv.y = t2[c][rq + 1];
        vv.z = t2[c][rq + 2];
        vv.w = t2[c][rq + 3];
        *(uint4*)(dst + (size_t)(c0 + c) * R + r0 + rq * 2) = vv;
    }
}

// two-tile variant: all 8 float4 loads issue before any LDS write.
__device__ __forceinline__ void tconv_tile2(const float* __restrict__ src,
                                            bf16_t* __restrict__ dst,
                                            int R, int C, int r0, int c0,
                                            unsigned (*t2a)[33],
                                            unsigned (*t2b)[33])
{
    const int tid = threadIdx.x;
    const int cl = (tid & 15) * 4;
    const int rh = tid >> 4;
    f32x4 va[2][2], vb[2][2];
#pragma unroll
    for (int i = 0; i < 2; ++i) {
        const int r = rh * 2 + i * 32;
        const float* s0 = src + (size_t)(r0 + r) * C + c0 + cl;
        va[i][0] = ntload4(s0);
        va[i][1] = ntload4(s0 + C);
        vb[i][0] = ntload4(s0 + 64);
        vb[i][1] = ntload4(s0 + C + 64);
    }
#pragma unroll
    for (int i = 0; i < 2; ++i) {
#pragma unroll
        for (int j = 0; j < 4; ++j) {
            t2a[cl + j][rh + i * 16] = pk2(va[i][0][j], va[i][1][j]);
            t2b[cl + j][rh + i * 16] = pk2(vb[i][0][j], vb[i][1][j]);
        }
    }
    __syncthreads();
    const int c2 = tid >> 3;
    const int rq = (tid & 7) * 4;
#pragma unroll
    for (int i = 0; i < 2; ++i) {
        const int c = c2 + i * 32;
        uint4 vv, ww;
        vv.x = t2a[c][rq + 0]; vv.y = t2a[c][rq + 1];
        vv.z = t2a[c][rq + 2]; vv.w = t2a[c][rq + 3];
        ww.x = t2b[c][rq + 0]; ww.y = t2b[c][rq + 1];
        ww.z = t2b[c][rq + 2]; ww.w = t2b[c][rq + 3];
        *(uint4*)(dst + (size_t)(c0 + c) * R + r0 + rq * 2) = vv;
        *(uint4*)(dst + (size_t)(c0 + 64 + c) * R + r0 + rq * 2) = ww;
    }
}

// tconvA (2-tile blocks) + prep_x. grid (22, 16, 19).
__global__ void tconvA_kernel(const float* __restrict__ w1, const float* __restrict__ w3,
                              const float* __restrict__ ws1, const float* __restrict__ ws3,
                              bf16_t* __restrict__ w1T, bf16_t* __restrict__ w3T,
                              bf16_t* __restrict__ ws1T, bf16_t* __restrict__ ws3T,
                              const float* __restrict__ x,
                              const float* __restrict__ gate_a,
                              const int* __restrict__ perm,
                              bf16_t* __restrict__ xs, bf16_t* __restrict__ xr)
{
    __shared__ unsigned t2a[64][33];
    __shared__ unsigned t2b[64][33];
    const int z = blockIdx.z;
    const size_t ms = (size_t)DDIM * FDIM;
    if (z < 18) {
        const float* src; bf16_t* dst;
        if (z < 8)       { src = w1 + (size_t)z * ms;       dst = w1T + (size_t)z * ms; }
        else if (z < 16) { src = w3 + (size_t)(z - 8) * ms; dst = w3T + (size_t)(z - 8) * ms; }
        else if (z == 16){ src = ws1;                        dst = ws1T; }
        else             { src = ws3;                        dst = ws3T; }
        tconv_tile2(src, dst, DDIM, FDIM, blockIdx.y * 64, blockIdx.x * 128,
                    t2a, t2b);
    } else {
        const int lin = blockIdx.x + blockIdx.y * 22;   // 0..351
        const int d = threadIdx.x * 4;
        for (int p = lin; p < A_TOK; p += 352) {
            f32x4 v = ntload4(x + (size_t)p * DDIM + d);
            bf16x4 o;
            o[0] = (bf16_t)v[0]; o[1] = (bf16_t)v[1];
            o[2] = (bf16_t)v[2]; o[3] = (bf16_t)v[3];
            *(bf16x4*)(xs + (size_t)p * DDIM + d) = o;

            const int tok = perm[p];
            const float g = gate_a[tok];
            f32x4 w = ntload4(x + (size_t)tok * DDIM + d);
            bf16x4 o2;
            o2[0] = (bf16_t)(w[0] * g); o2[1] = (bf16_t)(w[1] * g);
            o2[2] = (bf16_t)(w[2] * g); o2[3] = (bf16_t)(w[3] * g);
            *(bf16x4*)(xr + (size_t)p * DDIM + d) = o2;
        }
    }
}

// ======================= bf16 GEMM machinery =======================
__device__ __forceinline__ void glds16(const bf16_t* g, bf16_t* l)
{
    __builtin_amdgcn_global_load_lds(
        (const __attribute__((address_space(1))) void*)g,
        (__attribute__((address_space(3))) void*)l, 16, 0, 0);
}

// stage 128 rows x 64 bf16, XOR-swizzled on 16B slots -- 0 bank conflicts
__device__ __forceinline__ void stage_swz(const bf16_t* __restrict__ src,
                                          size_t stride, bf16_t* lds, int tid)
{
#pragma unroll
    for (int i = 0; i < 4; ++i) {
        int o = i * 256 + tid;
        int row = o >> 3;
        int slot = o & 7;
        int srcSlot = slot ^ (row & 7);
        glds16(src + (size_t)row * stride + srcSlot * 8, lds + (size_t)o * 8);
    }
}

// gathered variant: per-thread row base pointers (4 rows/thread), same swizzle.
__device__ __forceinline__ void stage_swz_gather(const bf16_t* const* rowPtr,
                                                 int k0, bf16_t* lds, int tid)
{
#pragma unroll
    for (int i = 0; i < 4; ++i) {
        int o = i * 256 + tid;
        int row = o >> 3;
        int slot = o & 7;
        int srcSlot = slot ^ (row & 7);
        glds16(rowPtr[i] + k0 + srcSlot * 8, lds + (size_t)o * 8);
    }
}

__device__ __forceinline__ int swz_off(int row, int g16)
{
    return row * 128 + ((g16 ^ (row & 7)) << 4);
}

// GEMM1 + tconvB heterogeneous launch (R16/R18 structure). grid (22, 32, 18):
//   z 0..8  : gemm1 (128x128 tile, BK=64, single buffer). Shared pass (z==8)
//             gathers A through perm -> mid_s written PERMUTED.
//   z 9..17 : tconvB tiles for w2[e]/ws2. Scratch aliases sA.
__global__ __launch_bounds__(256, 2)
void gemm1_bf16(const bf16_t* __restrict__ xr, const bf16_t* __restrict__ xs,
                const bf16_t* __restrict__ w1T, const bf16_t* __restrict__ w3T,
                const bf16_t* __restrict__ ws1T, const bf16_t* __restrict__ ws3T,
                const int* __restrict__ offsets, const int* __restrict__ perm,
                bf16_t* __restrict__ mid_r, bf16_t* __restrict__ mid_s,
                const float* __restrict__ w2, const float* __restrict__ ws2,
                bf16_t* __restrict__ w2T, bf16_t* __restrict__ ws2T)
{
    __shared__ __align__(16) bf16_t sA[128 * 64];
    __shared__ __align__(16) bf16_t sB1[128 * 64];
    __shared__ __align__(16) bf16_t sB3[128 * 64];

    const int g = blockIdx.z;
    if (g >= 9) {
        const int z2 = g - 9;
        const size_t ms = (size_t)DDIM * FDIM;
        const float* src; bf16_t* dst;
        if (z2 < 8) { src = w2 + (size_t)z2 * ms; dst = w2T + (size_t)z2 * ms; }
        else        { src = ws2;                   dst = ws2T; }
        const int lin = blockIdx.x + blockIdx.y * 22;   // 0..703
        const int rt = lin >> 4, ct = lin & 15;         // 44 x 16 tiles
        tconv_tile(src, dst, FDIM, DDIM, rt * 64, ct * 64,
                   (unsigned (*)[33])sA);
        return;
    }

    const int n0 = blockIdx.x * 128;
    int m0, mEnd;
    const bf16_t *pw1, *pw3;
    bf16_t* pout;
    if (g < NEXP) {
        int s = offsets[g], e = offsets[g + 1];
        m0 = s + blockIdx.y * 128;
        if (m0 >= e) return;
        mEnd = e;
        pw1 = w1T + (size_t)g * DDIM * FDIM;
        pw3 = w3T + (size_t)g * DDIM * FDIM;
        pout = mid_r;
    } else {
        m0 = blockIdx.y * 128;
        mEnd = A_TOK;
        pw1 = ws1T; pw3 = ws3T; pout = mid_s;
    }

    const int tid  = threadIdx.x;
    const int lane = tid & 63;
    const int wid  = tid >> 6;
    const int wm   = wid >> 1, wn = wid & 1;
    const int fr   = lane & 15;
    const int fq   = lane >> 4;

    f32x4 acc1[4][4], acc3[4][4];
#pragma unroll
    for (int i = 0; i < 4; ++i)
#pragma unroll
        for (int j = 0; j < 4; ++j) {
            acc1[i][j] = (f32x4){0.f, 0.f, 0.f, 0.f};
            acc3[i][j] = (f32x4){0.f, 0.f, 0.f, 0.f};
        }

    const int baseRow = tid >> 3;
    const bf16_t* rowPtr[4];
#pragma unroll
    for (int i = 0; i < 4; ++i) {
        int rr = m0 + baseRow + 32 * i;
        int rc = rr < mEnd ? rr : m0;          // clamp; masked at store
        rowPtr[i] = (g < NEXP) ? (xr + (size_t)rc * DDIM)
                               : (xs + (size_t)perm[rc] * DDIM);
    }

    const bf16_t* srcB1 = pw1 + (size_t)n0 * DDIM;
    const bf16_t* srcB3 = pw3 + (size_t)n0 * DDIM;

    for (int k0 = 0; k0 < DDIM; k0 += 64) {
        stage_swz_gather(rowPtr, k0, sA, tid);
        stage_swz(srcB1 + k0, DDIM, sB1, tid);
        stage_swz(srcB3 + k0, DDIM, sB3, tid);
        __syncthreads();

#pragma unroll
        for (int s = 0; s < 2; ++s) {
            const int kg = s * 4 + fq;
            bf16x8 af[4], b1f[4], b3f[4];
#pragma unroll
            for (int mi = 0; mi < 4; ++mi) {
                int r = wm * 64 + mi * 16 + fr;
                af[mi] = *(const bf16x8*)((const char*)sA + swz_off(r, kg));
            }
#pragma unroll
            for (int ni = 0; ni < 4; ++ni) {
                int r = wn * 64 + ni * 16 + fr;
                b1f[ni] = *(const bf16x8*)((const char*)sB1 + swz_off(r, kg));
                b3f[ni] = *(const bf16x8*)((const char*)sB3 + swz_off(r, kg));
            }
#pragma unroll
            for (int mi = 0; mi < 4; ++mi)
#pragma unroll
                for (int ni = 0; ni < 4; ++ni) {
                    acc1[mi][ni] = __builtin_amdgcn_mfma_f32_16x16x32_bf16(af[mi], b1f[ni], acc1[mi][ni], 0, 0, 0);
                    acc3[mi][ni] = __builtin_amdgcn_mfma_f32_16x16x32_bf16(af[mi], b3f[ni], acc3[mi][ni], 0, 0, 0);
                }
        }
        __syncthreads();
    }

#pragma unroll
    for (int mi = 0; mi < 4; ++mi) {
        int prow_b = m0 + wm * 64 + mi * 16 + fq * 4;
#pragma unroll
        for (int r = 0; r < 4; ++r) {
            int prow = prow_b + r;
            if (prow < mEnd) {
#pragma unroll
                for (int ni = 0; ni < 4; ++ni) {
                    float h1 = acc1[mi][ni][r];
                    float h3 = acc3[mi][ni][r];
                    float vv = h1 / (1.0f + __expf(-h1)) * h3;
                    int col = n0 + wn * 64 + ni * 16 + fr;
                    pout[(size_t)prow * FDIM + col] = (bf16_t)vv;
                }
            }
        }
    }
}

// GEMM2: ONE plain GEMM with K-concatenation + R19 2-phase double buffer.
//   out[perm[r]] = [mid_r[r] | mid_s[r]] @ [w2T[e] | ws2T]^T, virtual K=5632.
// 128x128 tile, BK=64, 64KB LDS (2x dbuf), split-K=4. Recipe: STAGE(next)
// issued BEFORE COMPUTE(cur); ONE __syncthreads per K-step (44 -> 23 barriers).
__global__ __launch_bounds__(256, 2)
void gemm2c_bf16(const bf16_t* __restrict__ mid_r, const bf16_t* __restrict__ mid_s,
                 const bf16_t* __restrict__ w2T, const bf16_t* __restrict__ ws2T,
                 const int* __restrict__ perm, const int* __restrict__ offsets,
                 float* __restrict__ out, bf16_t* __restrict__ outP1,
                 bf16_t* __restrict__ outP2, bf16_t* __restrict__ outP3)
{
    const int e   = blockIdx.z;
    const int nb  = blockIdx.x & 7;
    const int spl = blockIdx.x >> 3;          // 0..3
    const int n0  = nb * 128;
    const int s   = offsets[e], eEnd = offsets[e + 1];
    const int m0  = s + blockIdx.y * 128;
    if (m0 >= eEnd) return;
    const int mEnd = eEnd;

    const bf16_t* baseA;
    const bf16_t* baseB;
    {
        int kOff = (spl & 1) * KSPL;
        if (spl < 2) {
            baseA = mid_r + (size_t)m0 * FDIM + kOff;
            baseB = w2T + (size_t)e * DDIM * FDIM + (size_t)n0 * FDIM + kOff;
        } else {
            baseA = mid_s + (size_t)m0 * FDIM + kOff;
            baseB = ws2T + (size_t)n0 * FDIM + kOff;
        }
    }

    __shared__ __align__(16) bf16_t sA[2][128 * 64];
    __shared__ __align__(16) bf16_t sB[2][128 * 64];

    const int tid  = threadIdx.x;
    const int lane = tid & 63;
    const int wid  = tid >> 6;
    const int wm   = wid >> 1, wn = wid & 1;
    const int fr   = lane & 15;
    const int fq   = lane >> 4;

    f32x4 acc[4][4];
#pragma unroll
    for (int i = 0; i < 4; ++i)
#pragma unroll
        for (int j = 0; j < 4; ++j)
            acc[i][j] = (f32x4){0.f, 0.f, 0.f, 0.f};

#define G2_COMPUTE(BUF) do {                                                  \
        _Pragma("unroll")                                                     \
        for (int ss = 0; ss < 2; ++ss) {                                      \
            const int kg = ss * 4 + fq;                                       \
            bf16x8 af[4], bf[4];                                              \
            _Pragma("unroll")                                                 \
            for (int mi = 0; mi < 4; ++mi) {                                  \
                int r = wm * 64 + mi * 16 + fr;                               \
                af[mi] = *(const bf16x8*)((const char*)sA[BUF] + swz_off(r, kg)); \
            }                                                                 \
            _Pragma("unroll")                                                 \
            for (int ni = 0; ni < 4; ++ni) {                                  \
                int r = wn * 64 + ni * 16 + fr;                               \
                bf[ni] = *(const bf16x8*)((const char*)sB[BUF] + swz_off(r, kg)); \
            }                                                                 \
            _Pragma("unroll")                                                 \
            for (int mi = 0; mi < 4; ++mi)                                    \
                _Pragma("unroll")                                             \
                for (int ni = 0; ni < 4; ++ni)                                \
                    acc[mi][ni] = __builtin_amdgcn_mfma_f32_16x16x32_bf16(    \
                        af[mi], bf[ni], acc[mi][ni], 0, 0, 0);                \
        }                                                                     \
    } while (0)

    const int NT = KSPL / 64;          // 22 K-tiles
    stage_swz(baseA, FDIM, sA[0], tid);
    stage_swz(baseB, FDIM, sB[0], tid);
    __syncthreads();
    for (int t = 0; t < NT - 1; ++t) {
        const int cur = t & 1, nxt = cur ^ 1;
        stage_swz(baseA + (t + 1) * 64, FDIM, sA[nxt], tid);
        stage_swz(baseB + (t + 1) * 64, FDIM, sB[nxt], tid);
        G2_COMPUTE(cur);
        __syncthreads();
    }
    G2_COMPUTE((NT - 1) & 1);
#undef G2_COMPUTE

    if (spl == 0) {
#pragma unroll
        for (int mi = 0; mi < 4; ++mi) {
            int prow_b = m0 + wm * 64 + mi * 16 + fq * 4;
#pragma unroll
            for (int r = 0; r < 4; ++r) {
                int prow = prow_b + r;
                if (prow < mEnd) {
                    int orow = perm[prow];
#pragma unroll
                    for (int ni = 0; ni < 4; ++ni) {
                        int col = n0 + wn * 64 + ni * 16 + fr;
                        out[(size_t)orow * DDIM + col] = acc[mi][ni][r];
                    }
                }
            }
        }
    } else {
        bf16_t* dst = (spl == 1) ? outP1 : (spl == 2) ? outP2 : outP3;
#pragma unroll
        for (int mi = 0; mi < 4; ++mi) {
            int prow_b = m0 + wm * 64 + mi * 16 + fq * 4;
#pragma unroll
            for (int r = 0; r < 4; ++r) {
                int prow = prow_b + r;
                if (prow < mEnd) {
                    int orow = perm[prow];
#pragma unroll
                    for (int ni = 0; ni < 4; ++ni) {
                        int col = n0 + wn * 64 + ni * 16 + fr;
                        dst[(size_t)orow * DDIM + col] = (bf16_t)acc[mi][ni][r];
                    }
                }
            }
        }
    }
}

// out += p1 + p2 + p3 (bf16 partials), vectorized
__global__ __launch_bounds__(256)
void add_out_kernel(float* __restrict__ out, const bf16_t* __restrict__ p1,
                    const bf16_t* __restrict__ p2, const bf16_t* __restrict__ p3)
{
    const size_t i = ((size_t)blockIdx.x * 256 + threadIdx.x) * 4;
    float4 a = *(const float4*)(out + i);
    bf16x4 b = *(const bf16x4*)(p1 + i);
    bf16x4 c = *(const bf16x4*)(p2 + i);
    bf16x4 d = *(const bf16x4*)(p3 + i);
    a.x += (float)b[0] + (float)c[0] + (float)d[0];
    a.y += (float)b[1] + (float)c[1] + (float)d[1];
    a.z += (float)b[2] + (float)c[2] + (float)d[2];
    a.w += (float)b[3] + (float)c[3] + (float)d[3];
    *(float4*)(out + i) = a;
}

// ======================= launch =======================
extern "C" void kernel_launch(void* const* d_in, const int* in_sizes, int n_in,
                              void* d_out, int out_size, void* d_ws, size_t ws_size,
                              hipStream_t stream)
{
    const float* x      = (const float*)d_in[0];
    const float* router = (const float*)d_in[1];
    const float* w1     = (const float*)d_in[2];
    const float* w3     = (const float*)d_in[3];
    const float* w2     = (const float*)d_in[4];
    const float* ws1    = (const float*)d_in[5];
    const float* ws3    = (const float*)d_in[6];
    const float* ws2    = (const float*)d_in[7];
    float* out = (float*)d_out;

    char* ws = (char*)d_ws;
    int*   idx_a   = (int*)(ws + 0);
    float* gate_a  = (float*)(ws + 16384);
    int*   offsets = (int*)(ws + 32832);
    int*   perm    = (int*)(ws + 33280);

    bf16_t* xs    = (bf16_t*)(ws + OFF_XS);
    bf16_t* xr    = (bf16_t*)(ws + OFF_XR);
    bf16_t* mid_s = (bf16_t*)(ws + OFF_MIDS);
    bf16_t* mid_r = (bf16_t*)(ws + OFF_MIDR);
    bf16_t* w1T   = (bf16_t*)(ws + OFF_W1T);
    bf16_t* w3T   = (bf16_t*)(ws + OFF_W3T);
    bf16_t* w2T   = (bf16_t*)(ws + OFF_W2T);
    bf16_t* ws1T  = (bf16_t*)(ws + OFF_WS1T);
    bf16_t* ws3T  = (bf16_t*)(ws + OFF_WS3T);
    bf16_t* ws2T  = (bf16_t*)(ws + OFF_WS2T);
    bf16_t* outP1 = (bf16_t*)(ws + OFF_OUTP1);  // alias w1T (dead after gemm1)
    bf16_t* outP2 = (bf16_t*)(ws + OFF_OUTP2);
    bf16_t* outP3 = (bf16_t*)(ws + OFF_OUTP3);

    score_kernel<<<A_TOK / 4, 256, 0, stream>>>(x, router, idx_a, gate_a);
    perm_kernel<<<1, 1024, 0, stream>>>(idx_a, offsets, perm);

    // tconvA 2-tile blocks (z 0..17) + prep_x (z 18)
    tconvA_kernel<<<dim3(22, 16, 19), 256, 0, stream>>>(
        w1, w3, ws1, ws3, w1T, w3T, ws1T, ws3T, x, gate_a, perm, xs, xr);

    // gemm1 (z 0..8) + tconvB (z 9..17)
    gemm1_bf16<<<dim3(22, 32, 18), 256, 0, stream>>>(
        xr, xs, w1T, w3T, ws1T, ws3T, offsets, perm, mid_r, mid_s,
        w2, ws2, w2T, ws2T);

    gemm2c_bf16<<<dim3(32, 32, NEXP), 256, 0, stream>>>(
        mid_r, mid_s, w2T, ws2T, perm, offsets, out, outP1, outP2, outP3);

    add_out_kernel<<<(A_TOK * DDIM) / (256 * 4), 256, 0, stream>>>(
        out, outP1, outP2, outP3);
}

// Round 20
// 292.880 us; speedup vs baseline: 1.0420x; 1.0420x over previous
//
#include <hip/hip_runtime.h>
#include <hip/hip_bf16.h>
#include <math.h>

#define A_TOK 4096
#define DDIM  1024
#define NEXP  8
#define FDIM  2816
#define KSPL  1408         // virtual K = 2*FDIM = 5632; per split = 22*64

typedef __bf16 bf16_t;
typedef __bf16 bf16x8 __attribute__((ext_vector_type(8)));
typedef __bf16 bf16x4 __attribute__((ext_vector_type(4)));
typedef __bf16 bf16x2 __attribute__((ext_vector_type(2)));
typedef float  f32x4  __attribute__((ext_vector_type(4)));

// ======================= workspace layout =======================
static constexpr size_t OFF_XS   = 65536;
static constexpr size_t OFF_XR   = OFF_XS   + (size_t)A_TOK * DDIM * 2;
static constexpr size_t OFF_MIDS = OFF_XR   + (size_t)(A_TOK + 128) * DDIM * 2;
static constexpr size_t OFF_MIDR = OFF_MIDS + (size_t)A_TOK * FDIM * 2;
static constexpr size_t OFF_W1T  = OFF_MIDR + (size_t)(A_TOK + 128) * FDIM * 2;
static constexpr size_t OFF_W3T  = OFF_W1T  + (size_t)NEXP * DDIM * FDIM * 2;
static constexpr size_t OFF_W2T  = OFF_W3T  + (size_t)NEXP * DDIM * FDIM * 2;
static constexpr size_t OFF_WS1T = OFF_W2T  + (size_t)NEXP * DDIM * FDIM * 2;
static constexpr size_t OFF_WS3T = OFF_WS1T + (size_t)DDIM * FDIM * 2;
static constexpr size_t OFF_WS2T = OFF_WS3T + (size_t)DDIM * FDIM * 2;
static constexpr size_t WS_NEED  = OFF_WS2T + (size_t)DDIM * FDIM * 2;   // ~209.5 MiB
// Split-K partials (bf16, 8.4MB each) alias the dead w1T region (last read by
// the gemm1 launch, which completes before gemm2c runs).
static constexpr size_t OFF_OUTP1 = OFF_W1T;
static constexpr size_t OFF_OUTP2 = OFF_OUTP1 + (size_t)A_TOK * DDIM * 2;
static constexpr size_t OFF_OUTP3 = OFF_OUTP2 + (size_t)A_TOK * DDIM * 2;

// Tuning ledger (measured):
//  R3: BK=64, 8-slot XOR swizzle, (256,2) -> gemm1 120.7us / 783 TF. Working pt.
//  R4: BK=32 dbuf -> REGRESSED (4-slot swizzle conflicts). REVERTED.
//  R5: XCD remap -> slower (latency-bound). REVERTED.
//  R6: launch_bounds(256,3) -> spills. REVERTED.
//  R7-R14: gemm2 ladder 180 -> ~72us (K-concat gemm2c, 32KB, splitK4).
//  R15: merged tconv + bf16 partials -> 311.8.
//  R16: heterogeneous riders (tconvB in gemm1, prep in tconvA) -> 298.4.
//  R17: splitting gemm1 to hide tconvA -> REGRESSED (compute must >> riders).
//  R18: tconvA 2-tile + nontemporal loads -> 293.0 BEST (this config).
//  R19: gemm2c 64KB dbuf -> 305.2 REGRESSED (residency 4->2; barrier still
//       drains vmcnt(0)). REVERTED. Schedule matrix exhausted at this
//       structure; composite floor reached.

// ======================= router: scores =======================
__global__ __launch_bounds__(256)
void score_kernel(const float* __restrict__ x,
                  const float* __restrict__ router,
                  int* __restrict__ idx_a,
                  float* __restrict__ gate_a)
{
    __shared__ float rT[NEXP][DDIM];
    const int tid = threadIdx.x;
    for (int i = tid; i < DDIM * NEXP; i += 256)
        rT[i & 7][i >> 3] = router[i];
    __syncthreads();

    const int wid = tid >> 6, lane = tid & 63;
    const int t = blockIdx.x * 4 + wid;
    const float* xr = x + (size_t)t * DDIM;

    double s[NEXP];
#pragma unroll
    for (int e = 0; e < NEXP; ++e) s[e] = 0.0;
#pragma unroll
    for (int i = 0; i < DDIM / 64; ++i) {
        int d = i * 64 + lane;
        float xv = xr[d];
#pragma unroll
        for (int e = 0; e < NEXP; ++e)
            s[e] += (double)xv * (double)rT[e][d];
    }
#pragma unroll
    for (int e = 0; e < NEXP; ++e) {
#pragma unroll
        for (int off = 32; off > 0; off >>= 1)
            s[e] += __shfl_xor(s[e], off);
    }
    if (lane == 0) {
        int best = 0; double bv = s[0];
#pragma unroll
        for (int e = 1; e < NEXP; ++e)
            if (s[e] > bv) { bv = s[e]; best = e; }
        idx_a[t] = best;
        gate_a[t] = 1.0f / (1.0f + expf(-(float)bv));
    }
}

// ======================= fused count + scan + scatter =======================
__global__ __launch_bounds__(1024)
void perm_kernel(const int* __restrict__ idx_a,
                 int* __restrict__ offsets,
                 int* __restrict__ perm)
{
    __shared__ int cnt[NEXP];
    __shared__ int base[NEXP];
    const int tid = threadIdx.x;
    if (tid < NEXP) cnt[tid] = 0;
    __syncthreads();

    int e[4];
#pragma unroll
    for (int j = 0; j < 4; ++j) {
        e[j] = idx_a[j * 1024 + tid];
        atomicAdd(&cnt[e[j]], 1);
    }
    __syncthreads();
    if (tid == 0) {
        int acc = 0;
#pragma unroll
        for (int k = 0; k < NEXP; ++k) {
            base[k] = acc; offsets[k] = acc; acc += cnt[k];
        }
        offsets[NEXP] = acc;
    }
    __syncthreads();
#pragma unroll
    for (int j = 0; j < 4; ++j) {
        int t = j * 1024 + tid;
        int pos = atomicAdd(&base[e[j]], 1);
        perm[pos] = t;
    }
}

// ======================= helpers =======================
__device__ __forceinline__ unsigned pk2(float a, float b)
{
    union { bf16x2 v; unsigned u; } x;
    x.v[0] = (bf16_t)a; x.v[1] = (bf16_t)b;
    return x.u;
}

__device__ __forceinline__ f32x4 ntload4(const float* p)
{
    return __builtin_nontemporal_load((const f32x4*)p);
}

// single-tile transpose+convert: src [R][C] fp32 -> dst [C][R] bf16, 64x64.
__device__ __forceinline__ void tconv_tile(const float* __restrict__ src,
                                           bf16_t* __restrict__ dst,
                                           int R, int C, int r0, int c0,
                                           unsigned (*t2)[33])
{
    const int tid = threadIdx.x;
    const int cl = (tid & 15) * 4;
    const int rh = tid >> 4;
#pragma unroll
    for (int i = 0; i < 2; ++i) {
        const int r = rh * 2 + i * 32;
        const float* s0 = src + (size_t)(r0 + r) * C + c0 + cl;
        f32x4 v0 = ntload4(s0);
        f32x4 v1 = ntload4(s0 + C);
        t2[cl + 0][rh + i * 16] = pk2(v0[0], v1[0]);
        t2[cl + 1][rh + i * 16] = pk2(v0[1], v1[1]);
        t2[cl + 2][rh + i * 16] = pk2(v0[2], v1[2]);
        t2[cl + 3][rh + i * 16] = pk2(v0[3], v1[3]);
    }
    __syncthreads();
    const int c2 = tid >> 3;
    const int rq = (tid & 7) * 4;
#pragma unroll
    for (int i = 0; i < 2; ++i) {
        const int c = c2 + i * 32;
        uint4 vv;
        vv.x = t2[c][rq + 0];
        vv.y = t2[c][rq + 1];
        vv.z = t2[c][rq + 2];
        vv.w = t2[c][rq + 3];
        *(uint4*)(dst + (size_t)(c0 + c) * R + r0 + rq * 2) = vv;
    }
}

// two-tile variant: all 8 float4 loads issue before any LDS write.
__device__ __forceinline__ void tconv_tile2(const float* __restrict__ src,
                                            bf16_t* __restrict__ dst,
                                            int R, int C, int r0, int c0,
                                            unsigned (*t2a)[33],
                                            unsigned (*t2b)[33])
{
    const int tid = threadIdx.x;
    const int cl = (tid & 15) * 4;
    const int rh = tid >> 4;
    f32x4 va[2][2], vb[2][2];
#pragma unroll
    for (int i = 0; i < 2; ++i) {
        const int r = rh * 2 + i * 32;
        const float* s0 = src + (size_t)(r0 + r) * C + c0 + cl;
        va[i][0] = ntload4(s0);
        va[i][1] = ntload4(s0 + C);
        vb[i][0] = ntload4(s0 + 64);
        vb[i][1] = ntload4(s0 + C + 64);
    }
#pragma unroll
    for (int i = 0; i < 2; ++i) {
#pragma unroll
        for (int j = 0; j < 4; ++j) {
            t2a[cl + j][rh + i * 16] = pk2(va[i][0][j], va[i][1][j]);
            t2b[cl + j][rh + i * 16] = pk2(vb[i][0][j], vb[i][1][j]);
        }
    }
    __syncthreads();
    const int c2 = tid >> 3;
    const int rq = (tid & 7) * 4;
#pragma unroll
    for (int i = 0; i < 2; ++i) {
        const int c = c2 + i * 32;
        uint4 vv, ww;
        vv.x = t2a[c][rq + 0]; vv.y = t2a[c][rq + 1];
        vv.z = t2a[c][rq + 2]; vv.w = t2a[c][rq + 3];
        ww.x = t2b[c][rq + 0]; ww.y = t2b[c][rq + 1];
        ww.z = t2b[c][rq + 2]; ww.w = t2b[c][rq + 3];
        *(uint4*)(dst + (size_t)(c0 + c) * R + r0 + rq * 2) = vv;
        *(uint4*)(dst + (size_t)(c0 + 64 + c) * R + r0 + rq * 2) = ww;
    }
}

// tconvA (2-tile blocks) + prep_x. grid (22, 16, 19).
__global__ void tconvA_kernel(const float* __restrict__ w1, const float* __restrict__ w3,
                              const float* __restrict__ ws1, const float* __restrict__ ws3,
                              bf16_t* __restrict__ w1T, bf16_t* __restrict__ w3T,
                              bf16_t* __restrict__ ws1T, bf16_t* __restrict__ ws3T,
                              const float* __restrict__ x,
                              const float* __restrict__ gate_a,
                              const int* __restrict__ perm,
                              bf16_t* __restrict__ xs, bf16_t* __restrict__ xr)
{
    __shared__ unsigned t2a[64][33];
    __shared__ unsigned t2b[64][33];
    const int z = blockIdx.z;
    const size_t ms = (size_t)DDIM * FDIM;
    if (z < 18) {
        const float* src; bf16_t* dst;
        if (z < 8)       { src = w1 + (size_t)z * ms;       dst = w1T + (size_t)z * ms; }
        else if (z < 16) { src = w3 + (size_t)(z - 8) * ms; dst = w3T + (size_t)(z - 8) * ms; }
        else if (z == 16){ src = ws1;                        dst = ws1T; }
        else             { src = ws3;                        dst = ws3T; }
        tconv_tile2(src, dst, DDIM, FDIM, blockIdx.y * 64, blockIdx.x * 128,
                    t2a, t2b);
    } else {
        const int lin = blockIdx.x + blockIdx.y * 22;   // 0..351
        const int d = threadIdx.x * 4;
        for (int p = lin; p < A_TOK; p += 352) {
            f32x4 v = ntload4(x + (size_t)p * DDIM + d);
            bf16x4 o;
            o[0] = (bf16_t)v[0]; o[1] = (bf16_t)v[1];
            o[2] = (bf16_t)v[2]; o[3] = (bf16_t)v[3];
            *(bf16x4*)(xs + (size_t)p * DDIM + d) = o;

            const int tok = perm[p];
            const float g = gate_a[tok];
            f32x4 w = ntload4(x + (size_t)tok * DDIM + d);
            bf16x4 o2;
            o2[0] = (bf16_t)(w[0] * g); o2[1] = (bf16_t)(w[1] * g);
            o2[2] = (bf16_t)(w[2] * g); o2[3] = (bf16_t)(w[3] * g);
            *(bf16x4*)(xr + (size_t)p * DDIM + d) = o2;
        }
    }
}

// ======================= bf16 GEMM machinery =======================
__device__ __forceinline__ void glds16(const bf16_t* g, bf16_t* l)
{
    __builtin_amdgcn_global_load_lds(
        (const __attribute__((address_space(1))) void*)g,
        (__attribute__((address_space(3))) void*)l, 16, 0, 0);
}

// stage 128 rows x 64 bf16, XOR-swizzled on 16B slots -- 0 bank conflicts
__device__ __forceinline__ void stage_swz(const bf16_t* __restrict__ src,
                                          size_t stride, bf16_t* lds, int tid)
{
#pragma unroll
    for (int i = 0; i < 4; ++i) {
        int o = i * 256 + tid;
        int row = o >> 3;
        int slot = o & 7;
        int srcSlot = slot ^ (row & 7);
        glds16(src + (size_t)row * stride + srcSlot * 8, lds + (size_t)o * 8);
    }
}

// gathered variant: per-thread row base pointers (4 rows/thread), same swizzle.
__device__ __forceinline__ void stage_swz_gather(const bf16_t* const* rowPtr,
                                                 int k0, bf16_t* lds, int tid)
{
#pragma unroll
    for (int i = 0; i < 4; ++i) {
        int o = i * 256 + tid;
        int row = o >> 3;
        int slot = o & 7;
        int srcSlot = slot ^ (row & 7);
        glds16(rowPtr[i] + k0 + srcSlot * 8, lds + (size_t)o * 8);
    }
}

__device__ __forceinline__ int swz_off(int row, int g16)
{
    return row * 128 + ((g16 ^ (row & 7)) << 4);
}

// GEMM1 + tconvB heterogeneous launch. grid (22, 32, 18):
//   z 0..8  : gemm1 (128x128 tile, BK=64, single buffer). Shared pass (z==8)
//             gathers A through perm -> mid_s written PERMUTED.
//   z 9..17 : tconvB tiles for w2[e]/ws2. Scratch aliases sA.
__global__ __launch_bounds__(256, 2)
void gemm1_bf16(const bf16_t* __restrict__ xr, const bf16_t* __restrict__ xs,
                const bf16_t* __restrict__ w1T, const bf16_t* __restrict__ w3T,
                const bf16_t* __restrict__ ws1T, const bf16_t* __restrict__ ws3T,
                const int* __restrict__ offsets, const int* __restrict__ perm,
                bf16_t* __restrict__ mid_r, bf16_t* __restrict__ mid_s,
                const float* __restrict__ w2, const float* __restrict__ ws2,
                bf16_t* __restrict__ w2T, bf16_t* __restrict__ ws2T)
{
    __shared__ __align__(16) bf16_t sA[128 * 64];
    __shared__ __align__(16) bf16_t sB1[128 * 64];
    __shared__ __align__(16) bf16_t sB3[128 * 64];

    const int g = blockIdx.z;
    if (g >= 9) {
        const int z2 = g - 9;
        const size_t ms = (size_t)DDIM * FDIM;
        const float* src; bf16_t* dst;
        if (z2 < 8) { src = w2 + (size_t)z2 * ms; dst = w2T + (size_t)z2 * ms; }
        else        { src = ws2;                   dst = ws2T; }
        const int lin = blockIdx.x + blockIdx.y * 22;   // 0..703
        const int rt = lin >> 4, ct = lin & 15;         // 44 x 16 tiles
        tconv_tile(src, dst, FDIM, DDIM, rt * 64, ct * 64,
                   (unsigned (*)[33])sA);
        return;
    }

    const int n0 = blockIdx.x * 128;
    int m0, mEnd;
    const bf16_t *pw1, *pw3;
    bf16_t* pout;
    if (g < NEXP) {
        int s = offsets[g], e = offsets[g + 1];
        m0 = s + blockIdx.y * 128;
        if (m0 >= e) return;
        mEnd = e;
        pw1 = w1T + (size_t)g * DDIM * FDIM;
        pw3 = w3T + (size_t)g * DDIM * FDIM;
        pout = mid_r;
    } else {
        m0 = blockIdx.y * 128;
        mEnd = A_TOK;
        pw1 = ws1T; pw3 = ws3T; pout = mid_s;
    }

    const int tid  = threadIdx.x;
    const int lane = tid & 63;
    const int wid  = tid >> 6;
    const int wm   = wid >> 1, wn = wid & 1;
    const int fr   = lane & 15;
    const int fq   = lane >> 4;

    f32x4 acc1[4][4], acc3[4][4];
#pragma unroll
    for (int i = 0; i < 4; ++i)
#pragma unroll
        for (int j = 0; j < 4; ++j) {
            acc1[i][j] = (f32x4){0.f, 0.f, 0.f, 0.f};
            acc3[i][j] = (f32x4){0.f, 0.f, 0.f, 0.f};
        }

    const int baseRow = tid >> 3;
    const bf16_t* rowPtr[4];
#pragma unroll
    for (int i = 0; i < 4; ++i) {
        int rr = m0 + baseRow + 32 * i;
        int rc = rr < mEnd ? rr : m0;          // clamp; masked at store
        rowPtr[i] = (g < NEXP) ? (xr + (size_t)rc * DDIM)
                               : (xs + (size_t)perm[rc] * DDIM);
    }

    const bf16_t* srcB1 = pw1 + (size_t)n0 * DDIM;
    const bf16_t* srcB3 = pw3 + (size_t)n0 * DDIM;

    for (int k0 = 0; k0 < DDIM; k0 += 64) {
        stage_swz_gather(rowPtr, k0, sA, tid);
        stage_swz(srcB1 + k0, DDIM, sB1, tid);
        stage_swz(srcB3 + k0, DDIM, sB3, tid);
        __syncthreads();

#pragma unroll
        for (int s = 0; s < 2; ++s) {
            const int kg = s * 4 + fq;
            bf16x8 af[4], b1f[4], b3f[4];
#pragma unroll
            for (int mi = 0; mi < 4; ++mi) {
                int r = wm * 64 + mi * 16 + fr;
                af[mi] = *(const bf16x8*)((const char*)sA + swz_off(r, kg));
            }
#pragma unroll
            for (int ni = 0; ni < 4; ++ni) {
                int r = wn * 64 + ni * 16 + fr;
                b1f[ni] = *(const bf16x8*)((const char*)sB1 + swz_off(r, kg));
                b3f[ni] = *(const bf16x8*)((const char*)sB3 + swz_off(r, kg));
            }
#pragma unroll
            for (int mi = 0; mi < 4; ++mi)
#pragma unroll
                for (int ni = 0; ni < 4; ++ni) {
                    acc1[mi][ni] = __builtin_amdgcn_mfma_f32_16x16x32_bf16(af[mi], b1f[ni], acc1[mi][ni], 0, 0, 0);
                    acc3[mi][ni] = __builtin_amdgcn_mfma_f32_16x16x32_bf16(af[mi], b3f[ni], acc3[mi][ni], 0, 0, 0);
                }
        }
        __syncthreads();
    }

#pragma unroll
    for (int mi = 0; mi < 4; ++mi) {
        int prow_b = m0 + wm * 64 + mi * 16 + fq * 4;
#pragma unroll
        for (int r = 0; r < 4; ++r) {
            int prow = prow_b + r;
            if (prow < mEnd) {
#pragma unroll
                for (int ni = 0; ni < 4; ++ni) {
                    float h1 = acc1[mi][ni][r];
                    float h3 = acc3[mi][ni][r];
                    float vv = h1 / (1.0f + __expf(-h1)) * h3;
                    int col = n0 + wn * 64 + ni * 16 + fr;
                    pout[(size_t)prow * FDIM + col] = (bf16_t)vv;
                }
            }
        }
    }
}

// GEMM2: ONE plain GEMM with K-concatenation (R14/R18 structure).
//   out[perm[r]] = [mid_r[r] | mid_s[r]] @ [w2T[e] | ws2T]^T, virtual K=5632.
// 128x128 tile, BK=64, 32KB LDS, split-K=4. Split 0 -> fp32 out;
// splits 1-3 -> bf16 partials.
__global__ __launch_bounds__(256, 2)
void gemm2c_bf16(const bf16_t* __restrict__ mid_r, const bf16_t* __restrict__ mid_s,
                 const bf16_t* __restrict__ w2T, const bf16_t* __restrict__ ws2T,
                 const int* __restrict__ perm, const int* __restrict__ offsets,
                 float* __restrict__ out, bf16_t* __restrict__ outP1,
                 bf16_t* __restrict__ outP2, bf16_t* __restrict__ outP3)
{
    const int e   = blockIdx.z;
    const int nb  = blockIdx.x & 7;
    const int spl = blockIdx.x >> 3;          // 0..3
    const int n0  = nb * 128;
    const int s   = offsets[e], eEnd = offsets[e + 1];
    const int m0  = s + blockIdx.y * 128;
    if (m0 >= eEnd) return;
    const int mEnd = eEnd;

    const bf16_t* baseA;
    const bf16_t* baseB;
    {
        int kOff = (spl & 1) * KSPL;
        if (spl < 2) {
            baseA = mid_r + (size_t)m0 * FDIM + kOff;
            baseB = w2T + (size_t)e * DDIM * FDIM + (size_t)n0 * FDIM + kOff;
        } else {
            baseA = mid_s + (size_t)m0 * FDIM + kOff;
            baseB = ws2T + (size_t)n0 * FDIM + kOff;
        }
    }

    __shared__ __align__(16) bf16_t sA[128 * 64];
    __shared__ __align__(16) bf16_t sB[128 * 64];

    const int tid  = threadIdx.x;
    const int lane = tid & 63;
    const int wid  = tid >> 6;
    const int wm   = wid >> 1, wn = wid & 1;
    const int fr   = lane & 15;
    const int fq   = lane >> 4;

    f32x4 acc[4][4];
#pragma unroll
    for (int i = 0; i < 4; ++i)
#pragma unroll
        for (int j = 0; j < 4; ++j)
            acc[i][j] = (f32x4){0.f, 0.f, 0.f, 0.f};

    for (int k0 = 0; k0 < KSPL; k0 += 64) {
        stage_swz(baseA + k0, FDIM, sA, tid);
        stage_swz(baseB + k0, FDIM, sB, tid);
        __syncthreads();

#pragma unroll
        for (int ss = 0; ss < 2; ++ss) {
            const int kg = ss * 4 + fq;
            bf16x8 af[4], bf[4];
#pragma unroll
            for (int mi = 0; mi < 4; ++mi) {
                int r = wm * 64 + mi * 16 + fr;
                af[mi] = *(const bf16x8*)((const char*)sA + swz_off(r, kg));
            }
#pragma unroll
            for (int ni = 0; ni < 4; ++ni) {
                int r = wn * 64 + ni * 16 + fr;
                bf[ni] = *(const bf16x8*)((const char*)sB + swz_off(r, kg));
            }
#pragma unroll
            for (int mi = 0; mi < 4; ++mi)
#pragma unroll
                for (int ni = 0; ni < 4; ++ni)
                    acc[mi][ni] = __builtin_amdgcn_mfma_f32_16x16x32_bf16(af[mi], bf[ni], acc[mi][ni], 0, 0, 0);
        }
        __syncthreads();
    }

    if (spl == 0) {
#pragma unroll
        for (int mi = 0; mi < 4; ++mi) {
            int prow_b = m0 + wm * 64 + mi * 16 + fq * 4;
#pragma unroll
            for (int r = 0; r < 4; ++r) {
                int prow = prow_b + r;
                if (prow < mEnd) {
                    int orow = perm[prow];
#pragma unroll
                    for (int ni = 0; ni < 4; ++ni) {
                        int col = n0 + wn * 64 + ni * 16 + fr;
                        out[(size_t)orow * DDIM + col] = acc[mi][ni][r];
                    }
                }
            }
        }
    } else {
        bf16_t* dst = (spl == 1) ? outP1 : (spl == 2) ? outP2 : outP3;
#pragma unroll
        for (int mi = 0; mi < 4; ++mi) {
            int prow_b = m0 + wm * 64 + mi * 16 + fq * 4;
#pragma unroll
            for (int r = 0; r < 4; ++r) {
                int prow = prow_b + r;
                if (prow < mEnd) {
                    int orow = perm[prow];
#pragma unroll
                    for (int ni = 0; ni < 4; ++ni) {
                        int col = n0 + wn * 64 + ni * 16 + fr;
                        dst[(size_t)orow * DDIM + col] = (bf16_t)acc[mi][ni][r];
                    }
                }
            }
        }
    }
}

// out += p1 + p2 + p3 (bf16 partials), vectorized
__global__ __launch_bounds__(256)
void add_out_kernel(float* __restrict__ out, const bf16_t* __restrict__ p1,
                    const bf16_t* __restrict__ p2, const bf16_t* __restrict__ p3)
{
    const size_t i = ((size_t)blockIdx.x * 256 + threadIdx.x) * 4;
    float4 a = *(const float4*)(out + i);
    bf16x4 b = *(const bf16x4*)(p1 + i);
    bf16x4 c = *(const bf16x4*)(p2 + i);
    bf16x4 d = *(const bf16x4*)(p3 + i);
    a.x += (float)b[0] + (float)c[0] + (float)d[0];
    a.y += (float)b[1] + (float)c[1] + (float)d[1];
    a.z += (float)b[2] + (float)c[2] + (float)d[2];
    a.w += (float)b[3] + (float)c[3] + (float)d[3];
    *(float4*)(out + i) = a;
}

// ======================= launch =======================
extern "C" void kernel_launch(void* const* d_in, const int* in_sizes, int n_in,
                              void* d_out, int out_size, void* d_ws, size_t ws_size,
                              hipStream_t stream)
{
    const float* x      = (const float*)d_in[0];
    const float* router = (const float*)d_in[1];
    const float* w1     = (const float*)d_in[2];
    const float* w3     = (const float*)d_in[3];
    const float* w2     = (const float*)d_in[4];
    const float* ws1    = (const float*)d_in[5];
    const float* ws3    = (const float*)d_in[6];
    const float* ws2    = (const float*)d_in[7];
    float* out = (float*)d_out;

    char* ws = (char*)d_ws;
    int*   idx_a   = (int*)(ws + 0);
    float* gate_a  = (float*)(ws + 16384);
    int*   offsets = (int*)(ws + 32832);
    int*   perm    = (int*)(ws + 33280);

    bf16_t* xs    = (bf16_t*)(ws + OFF_XS);
    bf16_t* xr    = (bf16_t*)(ws + OFF_XR);
    bf16_t* mid_s = (bf16_t*)(ws + OFF_MIDS);
    bf16_t* mid_r = (bf16_t*)(ws + OFF_MIDR);
    bf16_t* w1T   = (bf16_t*)(ws + OFF_W1T);
    bf16_t* w3T   = (bf16_t*)(ws + OFF_W3T);
    bf16_t* w2T   = (bf16_t*)(ws + OFF_W2T);
    bf16_t* ws1T  = (bf16_t*)(ws + OFF_WS1T);
    bf16_t* ws3T  = (bf16_t*)(ws + OFF_WS3T);
    bf16_t* ws2T  = (bf16_t*)(ws + OFF_WS2T);
    bf16_t* outP1 = (bf16_t*)(ws + OFF_OUTP1);  // alias w1T (dead after gemm1)
    bf16_t* outP2 = (bf16_t*)(ws + OFF_OUTP2);
    bf16_t* outP3 = (bf16_t*)(ws + OFF_OUTP3);

    score_kernel<<<A_TOK / 4, 256, 0, stream>>>(x, router, idx_a, gate_a);
    perm_kernel<<<1, 1024, 0, stream>>>(idx_a, offsets, perm);

    // tconvA 2-tile blocks (z 0..17) + prep_x (z 18)
    tconvA_kernel<<<dim3(22, 16, 19), 256, 0, stream>>>(
        w1, w3, ws1, ws3, w1T, w3T, ws1T, ws3T, x, gate_a, perm, xs, xr);

    // gemm1 (z 0..8) + tconvB (z 9..17)
    gemm1_bf16<<<dim3(22, 32, 18), 256, 0, stream>>>(
        xr, xs, w1T, w3T, ws1T, ws3T, offsets, perm, mid_r, mid_s,
        w2, ws2, w2T, ws2T);

    gemm2c_bf16<<<dim3(32, 32, NEXP), 256, 0, stream>>>(
        mid_r, mid_s, w2T, ws2T, perm, offsets, out, outP1, outP2, outP3);

    add_out_kernel<<<(A_TOK * DDIM) / (256 * 4), 256, 0, stream>>>(
        out, outP1, outP2, outP3);
}